// Round 12
// baseline (116.507 us; speedup 1.0000x reference)
//
#include <hip/hip_runtime.h>
#include <math.h>

// ---------------- constants ----------------
#define WS 11
#define PAD 10
#define NC 48            // 16 batch * 3 channels
#define C1V 1.0e-4f
#define C2V 9.0e-4f
#define PLROWS 42        // fixed row-conv plane: 32 outputs + 10 carry
#define RST 65           // v2f row stride (64 cols + 1 pad)

// packed fp32 pair -> clang emits v_pk_fma_f32 (VOP3P) on gfx950
typedef float v2f __attribute__((ext_vector_type(2)));

struct Params { float g[WS]; };
struct ROff { int off[5]; int cnt[5]; float inv[5]; };

// ---- one row-conv unit: 4 output cols, packed channels (s,d) / (s^2,d^2) ----
__device__ __forceinline__ void row_conv_unit(
    const float* __restrict__ rowa, const float* __restrict__ rowb,
    const int xq[4], int cg,
    v2f* __restrict__ rowSD, v2f* __restrict__ rowE2, const Params& P)
{
    v2f msd[4] = {{0,0},{0,0},{0,0},{0,0}};
    v2f me2[4] = {{0,0},{0,0},{0,0},{0,0}};
#pragma unroll
    for (int q = 0; q < 4; ++q) {
        const float4 va = *(const float4*)(rowa + xq[q]);
        const float4 vb = *(const float4*)(rowb + xq[q]);
        const float fa[4] = {va.x, va.y, va.z, va.w};
        const float fb[4] = {vb.x, vb.y, vb.z, vb.w};
#pragma unroll
        for (int e = 0; e < 4; ++e) {
            const int i = q * 4 + e;                 // window position 0..15
            v2f sd; sd.x = fa[e] + fb[e]; sd.y = fa[e] - fb[e];
            const v2f sq = sd * sd;                  // v_pk_mul_f32
#pragma unroll
            for (int j = 0; j < 4; ++j) {
                const int k = i - j;
                if (k >= 0 && k < WS) {
                    const float g = P.g[k];
                    msd[j] += g * sd;                // v_pk_fma_f32
                    me2[j] += g * sq;                // v_pk_fma_f32
                }
            }
        }
    }
#pragma unroll
    for (int j = 0; j < 4; ++j) {
        rowSD[cg*4 + j] = msd[j];
        rowE2[cg*4 + j] = me2[j];
    }
}

// ---------------- wide sliding-strip SSIM (+pool) kernel ----------------
// 64-wide strips, 512-thread blocks: LDS 43.7KB -> 3 blocks/CU = 24 waves/CU
// (vs 14 at 32-wide) for latency hiding; column halo 76/64 vs 44/32.
// Same per-thread roles as before, masks widened. R8/R11 carry structure.
// NO min-waves launch-bounds hint (R9: hint-derived VGPR cap = spill storm).
template<int CH, int POOL>
__global__ __launch_bounds__(512) void ssim_strip_kernel(
    const float* __restrict__ img1, const float* __restrict__ img2,
    float* __restrict__ pool1, float* __restrict__ pool2,
    int H, int OH, int tilesX, Params P,
    float2* __restrict__ partial, int partial_off)
{
    __shared__ v2f rpSD[PLROWS][RST];   // (ms, md)
    __shared__ v2f rpE2[PLROWS][RST];   // (Es2, Ed2)
    __shared__ float reds[8], redc[8];
    const int tid   = threadIdx.x;
    const int tileX = blockIdx.x % tilesX;
    const int ty    = blockIdx.x / tilesX;
    const int img   = blockIdx.y;
    const size_t ib = (size_t)img * H * H;
    const float* __restrict__ p1 = img1 + ib;
    const float* __restrict__ p2 = img2 + ib;
    const int ox0 = tileX * 64;
    const int oy0 = ty * (CH * 32);

    // fixed per-thread roles (64-wide geometry)
    const int r_unit = tid >> 4;          // 0..31: row-conv row within chunk
    const int cg     = tid & 15;          // row-conv col group (16 x 4 = 64 cols)
    int xq[4];                            // clamped, constant across all rows
#pragma unroll
    for (int q = 0; q < 4; ++q) xq[q] = min(ox0 + cg*4 + q*4, H - 4);

    const int cc  = tid & 63;             // col-conv column
    const int r0c = (tid >> 6) * 4;       // col-conv first row in chunk (0..28)

    // preload strip rows 0..9 -> slots 0..9 (160 units)
    if (tid < 160) {
        const int y = min(oy0 + r_unit, H - 1);   // r_unit = tid>>4 in 0..9 here
        row_conv_unit(p1 + (size_t)y*H, p2 + (size_t)y*H, xq, cg,
                      &rpSD[r_unit][0], &rpE2[r_unit][0], P);
    }

    float ssim_acc = 0.f, cs_acc = 0.f;

    for (int t = 0; t < CH; ++t) {
        // ---- row conv: rows t*32+10 .. t*32+41 -> slots 10..41 (1/thread) ----
        {
            const int y = min(oy0 + t*32 + 10 + r_unit, H - 1);
            row_conv_unit(p1 + (size_t)y*H, p2 + (size_t)y*H, xq, cg,
                          &rpSD[10 + r_unit][0], &rpE2[10 + r_unit][0], P);
        }
        __syncthreads();

        // ---- col conv, half-batched reads + packed FMA ----
        v2f Asd[4] = {{0,0},{0,0},{0,0},{0,0}};
        v2f Ae2[4] = {{0,0},{0,0},{0,0},{0,0}};
        {
            v2f bsd[7], be2[7];
#pragma unroll
            for (int k = 0; k < 7; ++k) {            // batch 1: rows r0c..r0c+6
                bsd[k] = rpSD[r0c + k][cc];
                be2[k] = rpE2[r0c + k][cc];
            }
#pragma unroll
            for (int k = 0; k < 7; ++k) {
#pragma unroll
                for (int j = 0; j < 4; ++j) {
                    const int tt = k - j;
                    if (tt >= 0 && tt < WS) {
                        const float g = P.g[tt];
                        Asd[j] += g * bsd[k];
                        Ae2[j] += g * be2[k];
                    }
                }
            }
#pragma unroll
            for (int k = 7; k < 14; ++k) {           // batch 2: rows r0c+7..r0c+13
                bsd[k-7] = rpSD[r0c + k][cc];
                be2[k-7] = rpE2[r0c + k][cc];
            }
#pragma unroll
            for (int k = 7; k < 14; ++k) {
#pragma unroll
                for (int j = 0; j < 4; ++j) {
                    const int tt = k - j;
                    if (tt >= 0 && tt < WS) {
                        const float g = P.g[tt];
                        Asd[j] += g * bsd[k-7];
                        Ae2[j] += g * be2[k-7];
                    }
                }
            }
        }
        const int ox = ox0 + cc;
#pragma unroll
        for (int j = 0; j < 4; ++j) {
            const int oy = oy0 + t*32 + r0c + j;
            if (oy < OH && ox < OH) {     // OW == OH (square)
                const float ms = Asd[j].x, md = Asd[j].y;
                const float Es = Ae2[j].x, Ed = Ae2[j].y;
                const float ms2 = ms*ms, md2 = md*md;
                const float mu12 = 0.25f * (ms2 - md2);
                const float musq = 0.5f  * (ms2 + md2);             // mu1^2+mu2^2
                const float v1 = 0.5f * (Es - Ed) - 2.f*mu12 + C2V; // 2*sig12+C2
                const float v2 = 0.5f * (Es + Ed) - musq + C2V;     // sig1+sig2+C2
                const float rv2 = __builtin_amdgcn_rcpf(v2);
                const float cs  = v1 * rv2;
                const float ssim = (2.f*mu12 + C1V) *
                                   __builtin_amdgcn_rcpf(musq + C1V) * cs;
                ssim_acc += ssim;
                cs_acc   += cs;
            }
        }

        // ---- fused 2x2 avg pool of this chunk's 64x32 core (1 out/thread) ----
        if (POOL) {
            const int px = tid & 31, py = tid >> 5;   // 32 x 16 pool outputs
            const int yy = oy0 + t*32 + 2*py;
            const int xx = ox0 + 2*px;
            const float2 a0 = *(const float2*)(p1 + (size_t)yy*H + xx);
            const float2 a1 = *(const float2*)(p1 + (size_t)(yy+1)*H + xx);
            const float2 b0 = *(const float2*)(p2 + (size_t)yy*H + xx);
            const float2 b1 = *(const float2*)(p2 + (size_t)(yy+1)*H + xx);
            const int h = H >> 1;
            const size_t ob = (size_t)img*h*h +
                              (size_t)(((oy0 + t*32) >> 1) + py)*h + (ox0 >> 1) + px;
            pool1[ob] = 0.25f * (a0.x + a0.y + a1.x + a1.y);
            pool2[ob] = 0.25f * (b0.x + b0.y + b1.x + b1.y);
        }

        // ---- carry: slots 32..41 -> slots 0..9 (10 rows x 64 cols, 2 planes)
        if (t + 1 < CH) {
            __syncthreads();              // col-conv reads of slots 0..9 done
            for (int u = tid; u < 640; u += 512) {
                const int r = u >> 6, c = u & 63;
                rpSD[r][c] = rpSD[32 + r][c];
                rpE2[r][c] = rpE2[32 + r][c];
            }
            __syncthreads();              // carry done before next row-conv
        }
    }

    // ---- deterministic block reduction -> one partial per block ----
#pragma unroll
    for (int off = 32; off > 0; off >>= 1) {
        ssim_acc += __shfl_down(ssim_acc, off);
        cs_acc   += __shfl_down(cs_acc, off);
    }
    const int wave = tid >> 6, lane = tid & 63;
    if (lane == 0) { reds[wave] = ssim_acc; redc[wave] = cs_acc; }
    __syncthreads();
    if (tid == 0) {
        float s = 0.f, cc2 = 0.f;
#pragma unroll
        for (int w = 0; w < 8; ++w) { s += reds[w]; cc2 += redc[w]; }
        partial[(size_t)partial_off + (size_t)blockIdx.y * gridDim.x + blockIdx.x] =
            make_float2(s, cc2);
    }
}

// ---------------- single fused reduce over all levels + final product ----------------
__global__ __launch_bounds__(256) void reduce_final_kernel(
    const float2* __restrict__ partial, ROff ro, float* __restrict__ out)
{
    __shared__ float sS[5], sC[5];
    __shared__ float reds[4], redc[4];
    const int tid = threadIdx.x;
    for (int l = 0; l < 5; ++l) {
        float s = 0.f, c = 0.f;
        for (int i = tid; i < ro.cnt[l]; i += 256) {
            const float2 v = partial[ro.off[l] + i];
            s += v.x; c += v.y;
        }
#pragma unroll
        for (int off = 32; off > 0; off >>= 1) {
            s += __shfl_down(s, off);
            c += __shfl_down(c, off);
        }
        const int wave = tid >> 6, lane = tid & 63;
        if (lane == 0) { reds[wave] = s; redc[wave] = c; }
        __syncthreads();
        if (tid == 0) {
            sS[l] = (reds[0] + reds[1] + reds[2] + reds[3]) * ro.inv[l];
            sC[l] = (redc[0] + redc[1] + redc[2] + redc[3]) * ro.inv[l];
        }
        __syncthreads();
    }
    if (tid == 0) {
        const float w[5] = {0.0448f, 0.2856f, 0.3001f, 0.2363f, 0.1333f};
        float prod = 1.f;
#pragma unroll
        for (int i = 0; i < 4; ++i)
            prod *= powf((sC[i] + 1.f) * 0.5f, w[i]);
        prod *= powf((sS[4] + 1.f) * 0.5f, w[4]);
        out[0] = prod;
    }
}

// ---------------- host launch ----------------
extern "C" void kernel_launch(void* const* d_in, const int* in_sizes, int n_in,
                              void* d_out, int out_size, void* d_ws, size_t ws_size,
                              hipStream_t stream)
{
    const float* img1 = (const float*)d_in[0];
    const float* img2 = (const float*)d_in[1];
    float* out = (float*)d_out;
    float* ws  = (float*)d_ws;

    // Gaussian window (sigma = 1.5), normalized
    Params P;
    {
        double g[WS], sum = 0.0;
        for (int i = 0; i < WS; ++i) {
            double x = (double)i - (WS / 2);
            g[i] = exp(-x * x / (2.0 * 1.5 * 1.5));
            sum += g[i];
        }
        for (int i = 0; i < WS; ++i) P.g[i] = (float)(g[i] / sum);
    }

    // workspace layout: pyramid levels 1..4 (both images), then partials
    float* p1[5]; float* p2[5];
    p1[0] = (float*)img1; p2[0] = (float*)img2;
    size_t o = 0;
    for (int l = 1; l < 5; ++l) {
        const int H = 512 >> l;
        p1[l] = ws + o; o += (size_t)NC * H * H;
        p2[l] = ws + o; o += (size_t)NC * H * H;
    }
    float2* partial = (float2*)(ws + o);
    (void)ws_size; (void)in_sizes; (void)n_in; (void)out_size;

    const int CHv[5] = {2, 2, 2, 2, 1};   // 32-row chunks per strip, per level
    ROff ro;
    {
        int off = 0;
        for (int l = 0; l < 5; ++l) {
            const int H = 512 >> l, OH = H - PAD;
            const int tilesX = (OH + 63) / 64;
            const int tilesY = (OH + CHv[l]*32 - 1) / (CHv[l]*32);
            ro.off[l] = off;
            ro.cnt[l] = tilesX * tilesY * NC;
            ro.inv[l] = 1.f / ((float)NC * OH * OH);
            off += ro.cnt[l];
        }
    }

    for (int l = 0; l < 5; ++l) {
        const int H = 512 >> l, OH = H - PAD;
        const int tilesX = (OH + 63) / 64;
        const int tilesY = (OH + CHv[l]*32 - 1) / (CHv[l]*32);
        const dim3 grid(tilesX * tilesY, NC);
        if (l < 4)
            ssim_strip_kernel<2,1><<<grid, 512, 0, stream>>>(
                p1[l], p2[l], p1[l+1], p2[l+1], H, OH, tilesX, P, partial, ro.off[l]);
        else
            ssim_strip_kernel<1,0><<<grid, 512, 0, stream>>>(
                p1[4], p2[4], nullptr, nullptr, H, OH, tilesX, P, partial, ro.off[4]);
    }

    reduce_final_kernel<<<1, 256, 0, stream>>>(partial, ro, out);
}

// Round 13
// 109.152 us; speedup vs baseline: 1.0674x; 1.0674x over previous
//
#include <hip/hip_runtime.h>
#include <math.h>

// ---------------- constants ----------------
#define WS 11
#define PAD 10
#define NC 48            // 16 batch * 3 channels
#define C1V 1.0e-4f
#define C2V 9.0e-4f
#define IH 42            // tile rows (32 outputs + 10 halo)
#define TW 32            // tile width / output cols

// packed fp32 pair -> clang emits v_pk_fma_f32 (VOP3P) on gfx950
typedef float v2f __attribute__((ext_vector_type(2)));

struct Params { float g[WS]; };
struct ROff { int off[5]; int cnt[5]; float inv[5]; };

// ---- one row-conv unit: 4 output cols, packed (s,d)+(s^2,d^2) -> one float4 ----
__device__ __forceinline__ void row_conv_unit(
    const float* __restrict__ rowa, const float* __restrict__ rowb,
    const int xq[4], int cg, float4* __restrict__ rprow, const Params& P)
{
    v2f msd[4] = {{0,0},{0,0},{0,0},{0,0}};
    v2f me2[4] = {{0,0},{0,0},{0,0},{0,0}};
#pragma unroll
    for (int q = 0; q < 4; ++q) {
        const float4 va = *(const float4*)(rowa + xq[q]);
        const float4 vb = *(const float4*)(rowb + xq[q]);
        const float fa[4] = {va.x, va.y, va.z, va.w};
        const float fb[4] = {vb.x, vb.y, vb.z, vb.w};
#pragma unroll
        for (int e = 0; e < 4; ++e) {
            const int i = q * 4 + e;                 // window position 0..15
            v2f sd; sd.x = fa[e] + fb[e]; sd.y = fa[e] - fb[e];
            const v2f sq = sd * sd;                  // v_pk_mul_f32
#pragma unroll
            for (int j = 0; j < 4; ++j) {
                const int k = i - j;
                if (k >= 0 && k < WS) {
                    const float g = P.g[k];
                    msd[j] += g * sd;                // v_pk_fma_f32
                    me2[j] += g * sq;                // v_pk_fma_f32
                }
            }
        }
    }
#pragma unroll
    for (int j = 0; j < 4; ++j)
        rprow[cg*4 + j] = make_float4(msd[j].x, msd[j].y, me2[j].x, me2[j].y);
}

// ---------------- independent-tile SSIM (+pool) kernel ----------------
// R2's proven structure: 42x32 tile, one UNSWIZZLED float4 plane (measured 0
// bank conflicts in R2; the R3 XOR swizzle *caused* 6.2M), 12288 independent
// blocks at level 0 (81% VALUBusy in R3 -> issue-rate, not stalls).
// + R11's packed v_pk_fma_f32 conv math (~-40% VALU instructions).
// grid: (tiles*tiles, NC); block: 256. Plain launch_bounds (R9: caps = spills).
template<int POOL>
__global__ __launch_bounds__(256) void ssim_tile_kernel(
    const float* __restrict__ img1, const float* __restrict__ img2,
    float* __restrict__ pool1, float* __restrict__ pool2,
    int H, int OH, int tilesX, Params P,
    float2* __restrict__ partial, int partial_off)
{
    __shared__ float4 rp[IH][TW];     // {ms, md, Es2, Ed2}
    __shared__ float reds[4], redc[4];
    const int tid   = threadIdx.x;
    const int tileX = blockIdx.x % tilesX;
    const int ty    = blockIdx.x / tilesX;
    const int img   = blockIdx.y;
    const size_t ib = (size_t)img * H * H;
    const float* __restrict__ p1 = img1 + ib;
    const float* __restrict__ p2 = img2 + ib;
    const int ox0 = tileX * TW;
    const int oy0 = ty * TW;

    // fixed per-thread roles
    const int r_unit = tid >> 3;          // 0..31: row-conv row
    const int cg     = tid & 7;           // row-conv col group
    int xq[4];                            // clamped, constant for this thread
#pragma unroll
    for (int q = 0; q < 4; ++q) xq[q] = min(ox0 + cg*4 + q*4, H - 4);

    const int cc  = tid & 31;             // col-conv column
    const int r0c = (tid >> 5) * 4;       // col-conv first row

    // ---- row conv: 42 rows x 8 groups = 336 units; threads 0..79 do row+32 ----
    {
        const int y = min(oy0 + r_unit, H - 1);
        row_conv_unit(p1 + (size_t)y*H, p2 + (size_t)y*H, xq, cg, &rp[r_unit][0], P);
    }
    if (tid < 80) {
        const int r2 = r_unit + 32;       // rows 32..41
        const int y = min(oy0 + r2, H - 1);
        row_conv_unit(p1 + (size_t)y*H, p2 + (size_t)y*H, xq, cg, &rp[r2][0], P);
    }
    __syncthreads();

    // ---- col conv, half-batched b128 reads + packed FMA ----
    v2f Asd[4] = {{0,0},{0,0},{0,0},{0,0}};
    v2f Ae2[4] = {{0,0},{0,0},{0,0},{0,0}};
    {
        float4 b[7];
#pragma unroll
        for (int k = 0; k < 7; ++k) b[k] = rp[r0c + k][cc];      // batch 1
#pragma unroll
        for (int k = 0; k < 7; ++k) {
            const v2f vsd = {b[k].x, b[k].y};
            const v2f ve2 = {b[k].z, b[k].w};
#pragma unroll
            for (int j = 0; j < 4; ++j) {
                const int tt = k - j;
                if (tt >= 0 && tt < WS) {
                    const float g = P.g[tt];
                    Asd[j] += g * vsd;
                    Ae2[j] += g * ve2;
                }
            }
        }
#pragma unroll
        for (int k = 7; k < 14; ++k) b[k-7] = rp[r0c + k][cc];   // batch 2
#pragma unroll
        for (int k = 7; k < 14; ++k) {
            const v2f vsd = {b[k-7].x, b[k-7].y};
            const v2f ve2 = {b[k-7].z, b[k-7].w};
#pragma unroll
            for (int j = 0; j < 4; ++j) {
                const int tt = k - j;
                if (tt >= 0 && tt < WS) {
                    const float g = P.g[tt];
                    Asd[j] += g * vsd;
                    Ae2[j] += g * ve2;
                }
            }
        }
    }

    float ssim_acc = 0.f, cs_acc = 0.f;
    const int ox = ox0 + cc;
#pragma unroll
    for (int j = 0; j < 4; ++j) {
        const int oy = oy0 + r0c + j;
        if (oy < OH && ox < OH) {         // OW == OH (square)
            const float ms = Asd[j].x, md = Asd[j].y;
            const float Es = Ae2[j].x, Ed = Ae2[j].y;
            const float ms2 = ms*ms, md2 = md*md;
            const float mu12 = 0.25f * (ms2 - md2);
            const float musq = 0.5f  * (ms2 + md2);             // mu1^2+mu2^2
            const float v1 = 0.5f * (Es - Ed) - 2.f*mu12 + C2V; // 2*sig12+C2
            const float v2 = 0.5f * (Es + Ed) - musq + C2V;     // sig1+sig2+C2
            const float rv2 = __builtin_amdgcn_rcpf(v2);
            const float cs  = v1 * rv2;
            const float ssim = (2.f*mu12 + C1V) *
                               __builtin_amdgcn_rcpf(musq + C1V) * cs;
            ssim_acc += ssim;
            cs_acc   += cs;
        }
    }

    // ---- fused 2x2 avg pool of the tile's 32x32 core (1 out/thread) ----
    if (POOL) {
        const int px = tid & 15, py = tid >> 4;
        const int yy = oy0 + 2*py;
        const int xx = ox0 + 2*px;
        const float2 a0 = *(const float2*)(p1 + (size_t)yy*H + xx);
        const float2 a1 = *(const float2*)(p1 + (size_t)(yy+1)*H + xx);
        const float2 b0 = *(const float2*)(p2 + (size_t)yy*H + xx);
        const float2 b1 = *(const float2*)(p2 + (size_t)(yy+1)*H + xx);
        const int h = H >> 1;
        const size_t ob = (size_t)img*h*h +
                          (size_t)((oy0 >> 1) + py)*h + (ox0 >> 1) + px;
        pool1[ob] = 0.25f * (a0.x + a0.y + a1.x + a1.y);
        pool2[ob] = 0.25f * (b0.x + b0.y + b1.x + b1.y);
    }

    // ---- deterministic block reduction -> one partial per block ----
#pragma unroll
    for (int off = 32; off > 0; off >>= 1) {
        ssim_acc += __shfl_down(ssim_acc, off);
        cs_acc   += __shfl_down(cs_acc, off);
    }
    const int wave = tid >> 6, lane = tid & 63;
    if (lane == 0) { reds[wave] = ssim_acc; redc[wave] = cs_acc; }
    __syncthreads();
    if (tid == 0) {
        const float s   = reds[0] + reds[1] + reds[2] + reds[3];
        const float cc2 = redc[0] + redc[1] + redc[2] + redc[3];
        partial[(size_t)partial_off + (size_t)blockIdx.y * gridDim.x + blockIdx.x] =
            make_float2(s, cc2);
    }
}

// ---------------- single fused reduce over all levels + final product ----------------
__global__ __launch_bounds__(256) void reduce_final_kernel(
    const float2* __restrict__ partial, ROff ro, float* __restrict__ out)
{
    __shared__ float sS[5], sC[5];
    __shared__ float reds[4], redc[4];
    const int tid = threadIdx.x;
    for (int l = 0; l < 5; ++l) {
        float s = 0.f, c = 0.f;
        for (int i = tid; i < ro.cnt[l]; i += 256) {
            const float2 v = partial[ro.off[l] + i];
            s += v.x; c += v.y;
        }
#pragma unroll
        for (int off = 32; off > 0; off >>= 1) {
            s += __shfl_down(s, off);
            c += __shfl_down(c, off);
        }
        const int wave = tid >> 6, lane = tid & 63;
        if (lane == 0) { reds[wave] = s; redc[wave] = c; }
        __syncthreads();
        if (tid == 0) {
            sS[l] = (reds[0] + reds[1] + reds[2] + reds[3]) * ro.inv[l];
            sC[l] = (redc[0] + redc[1] + redc[2] + redc[3]) * ro.inv[l];
        }
        __syncthreads();
    }
    if (tid == 0) {
        const float w[5] = {0.0448f, 0.2856f, 0.3001f, 0.2363f, 0.1333f};
        float prod = 1.f;
#pragma unroll
        for (int i = 0; i < 4; ++i)
            prod *= powf((sC[i] + 1.f) * 0.5f, w[i]);
        prod *= powf((sS[4] + 1.f) * 0.5f, w[4]);
        out[0] = prod;
    }
}

// ---------------- host launch ----------------
extern "C" void kernel_launch(void* const* d_in, const int* in_sizes, int n_in,
                              void* d_out, int out_size, void* d_ws, size_t ws_size,
                              hipStream_t stream)
{
    const float* img1 = (const float*)d_in[0];
    const float* img2 = (const float*)d_in[1];
    float* out = (float*)d_out;
    float* ws  = (float*)d_ws;

    // Gaussian window (sigma = 1.5), normalized
    Params P;
    {
        double g[WS], sum = 0.0;
        for (int i = 0; i < WS; ++i) {
            double x = (double)i - (WS / 2);
            g[i] = exp(-x * x / (2.0 * 1.5 * 1.5));
            sum += g[i];
        }
        for (int i = 0; i < WS; ++i) P.g[i] = (float)(g[i] / sum);
    }

    // workspace layout: pyramid levels 1..4 (both images), then partials
    float* p1[5]; float* p2[5];
    p1[0] = (float*)img1; p2[0] = (float*)img2;
    size_t o = 0;
    for (int l = 1; l < 5; ++l) {
        const int H = 512 >> l;
        p1[l] = ws + o; o += (size_t)NC * H * H;
        p2[l] = ws + o; o += (size_t)NC * H * H;
    }
    float2* partial = (float2*)(ws + o);
    (void)ws_size; (void)in_sizes; (void)n_in; (void)out_size;

    ROff ro;
    {
        int off = 0;
        for (int l = 0; l < 5; ++l) {
            const int H = 512 >> l, OH = H - PAD;
            const int tiles = (OH + TW - 1) / TW;
            ro.off[l] = off;
            ro.cnt[l] = tiles * tiles * NC;
            ro.inv[l] = 1.f / ((float)NC * OH * OH);
            off += ro.cnt[l];
        }
    }

    for (int l = 0; l < 5; ++l) {
        const int H = 512 >> l, OH = H - PAD;
        const int tiles = (OH + TW - 1) / TW;
        const dim3 grid(tiles * tiles, NC);
        if (l < 4)
            ssim_tile_kernel<1><<<grid, 256, 0, stream>>>(
                p1[l], p2[l], p1[l+1], p2[l+1], H, OH, tiles, P, partial, ro.off[l]);
        else
            ssim_tile_kernel<0><<<grid, 256, 0, stream>>>(
                p1[4], p2[4], nullptr, nullptr, H, OH, tiles, P, partial, ro.off[4]);
    }

    reduce_final_kernel<<<1, 256, 0, stream>>>(partial, ro, out);
}

// Round 14
// 101.674 us; speedup vs baseline: 1.1459x; 1.0735x over previous
//
#include <hip/hip_runtime.h>
#include <math.h>

// ---------------- constants ----------------
#define WS 11
#define PAD 10
#define NC 48            // 16 batch * 3 channels
#define C1V 1.0e-4f
#define C2V 9.0e-4f
#define PLROWS 42        // fixed row-conv plane: 32 outputs + 10 carry
#define RST 33           // v2f row stride (264B; odd -> 2-way max on b64)

// packed fp32 pair -> clang emits v_pk_fma_f32 (VOP3P) on gfx950
typedef float v2f __attribute__((ext_vector_type(2)));

struct Params { float g[WS]; };
struct ROff { int off[5]; int cnt[5]; float inv[5]; };

// ---- one row-conv unit: 4 output cols, packed channels (s,d) / (s^2,d^2) ----
__device__ __forceinline__ void row_conv_unit(
    const float* __restrict__ rowa, const float* __restrict__ rowb,
    const int xq[4], int cg,
    v2f* __restrict__ rowSD, v2f* __restrict__ rowE2, const Params& P)
{
    v2f msd[4] = {{0,0},{0,0},{0,0},{0,0}};
    v2f me2[4] = {{0,0},{0,0},{0,0},{0,0}};
#pragma unroll
    for (int q = 0; q < 4; ++q) {
        const float4 va = *(const float4*)(rowa + xq[q]);
        const float4 vb = *(const float4*)(rowb + xq[q]);
        const float fa[4] = {va.x, va.y, va.z, va.w};
        const float fb[4] = {vb.x, vb.y, vb.z, vb.w};
#pragma unroll
        for (int e = 0; e < 4; ++e) {
            const int i = q * 4 + e;                 // window position 0..15
            v2f sd; sd.x = fa[e] + fb[e]; sd.y = fa[e] - fb[e];
            const v2f sq = sd * sd;                  // v_pk_mul_f32
#pragma unroll
            for (int j = 0; j < 4; ++j) {
                const int k = i - j;
                if (k >= 0 && k < WS) {
                    const float g = P.g[k];
                    msd[j] += g * sd;                // v_pk_fma_f32
                    me2[j] += g * sq;                // v_pk_fma_f32
                }
            }
        }
    }
#pragma unroll
    for (int j = 0; j < 4; ++j) {
        rowSD[cg*4 + j] = msd[j];
        rowE2[cg*4 + j] = me2[j];
    }
}

// ---------------- sliding-strip SSIM (+pool) kernel ----------------
// Session-best configuration (R11, 101.7us total): R8 base structure (single
// 42-row plane + carry), packed v_pk_fma_f32 math, half-batched col-conv LDS
// reads. Level-0 is pinned at ~70us across all structural variants (R3-R13);
// see journal: phase-serialized floor (VALU+LDS chain+HBM in-flight limit).
// NO min-waves launch-bounds hint (R9: hint-derived VGPR cap = spill storm).
template<int CH, int POOL>
__global__ __launch_bounds__(256) void ssim_strip_kernel(
    const float* __restrict__ img1, const float* __restrict__ img2,
    float* __restrict__ pool1, float* __restrict__ pool2,
    int H, int OH, int tilesX, Params P,
    float2* __restrict__ partial, int partial_off)
{
    __shared__ v2f rpSD[PLROWS][RST];   // (ms, md)
    __shared__ v2f rpE2[PLROWS][RST];   // (Es2, Ed2)
    __shared__ float reds[4], redc[4];
    const int tid   = threadIdx.x;
    const int tileX = blockIdx.x % tilesX;
    const int ty    = blockIdx.x / tilesX;
    const int img   = blockIdx.y;
    const size_t ib = (size_t)img * H * H;
    const float* __restrict__ p1 = img1 + ib;
    const float* __restrict__ p2 = img2 + ib;
    const int ox0 = tileX * 32;
    const int oy0 = ty * (CH * 32);

    // fixed per-thread roles
    const int r_unit = tid >> 3;          // 0..31: row-conv row within chunk
    const int cg     = tid & 7;           // row-conv col group
    int xq[4];                            // clamped, constant across all rows
#pragma unroll
    for (int q = 0; q < 4; ++q) xq[q] = min(ox0 + cg*4 + q*4, H - 4);

    const int cc  = tid & 31;             // col-conv column
    const int r0c = (tid >> 5) * 4;       // col-conv first row in chunk

    // preload strip rows 0..9 -> slots 0..9
    if (tid < 80) {
        const int y = min(oy0 + r_unit, H - 1);
        row_conv_unit(p1 + (size_t)y*H, p2 + (size_t)y*H, xq, cg,
                      &rpSD[r_unit][0], &rpE2[r_unit][0], P);
    }

    float ssim_acc = 0.f, cs_acc = 0.f;

    for (int t = 0; t < CH; ++t) {
        // ---- row conv: rows t*32+10 .. t*32+41 -> slots 10..41 (1/thread) ----
        {
            const int y = min(oy0 + t*32 + 10 + r_unit, H - 1);
            row_conv_unit(p1 + (size_t)y*H, p2 + (size_t)y*H, xq, cg,
                          &rpSD[10 + r_unit][0], &rpE2[10 + r_unit][0], P);
        }
        __syncthreads();

        // ---- col conv, half-batched reads + packed FMA ----
        v2f Asd[4] = {{0,0},{0,0},{0,0},{0,0}};
        v2f Ae2[4] = {{0,0},{0,0},{0,0},{0,0}};
        {
            v2f bsd[7], be2[7];
#pragma unroll
            for (int k = 0; k < 7; ++k) {            // batch 1: rows r0c..r0c+6
                bsd[k] = rpSD[r0c + k][cc];
                be2[k] = rpE2[r0c + k][cc];
            }
#pragma unroll
            for (int k = 0; k < 7; ++k) {
#pragma unroll
                for (int j = 0; j < 4; ++j) {
                    const int tt = k - j;
                    if (tt >= 0 && tt < WS) {
                        const float g = P.g[tt];
                        Asd[j] += g * bsd[k];
                        Ae2[j] += g * be2[k];
                    }
                }
            }
#pragma unroll
            for (int k = 7; k < 14; ++k) {           // batch 2: rows r0c+7..r0c+13
                bsd[k-7] = rpSD[r0c + k][cc];
                be2[k-7] = rpE2[r0c + k][cc];
            }
#pragma unroll
            for (int k = 7; k < 14; ++k) {
#pragma unroll
                for (int j = 0; j < 4; ++j) {
                    const int tt = k - j;
                    if (tt >= 0 && tt < WS) {
                        const float g = P.g[tt];
                        Asd[j] += g * bsd[k-7];
                        Ae2[j] += g * be2[k-7];
                    }
                }
            }
        }
        const int ox = ox0 + cc;
#pragma unroll
        for (int j = 0; j < 4; ++j) {
            const int oy = oy0 + t*32 + r0c + j;
            if (oy < OH && ox < OH) {     // OW == OH (square)
                const float ms = Asd[j].x, md = Asd[j].y;
                const float Es = Ae2[j].x, Ed = Ae2[j].y;
                const float ms2 = ms*ms, md2 = md*md;
                const float mu12 = 0.25f * (ms2 - md2);
                const float musq = 0.5f  * (ms2 + md2);             // mu1^2+mu2^2
                const float v1 = 0.5f * (Es - Ed) - 2.f*mu12 + C2V; // 2*sig12+C2
                const float v2 = 0.5f * (Es + Ed) - musq + C2V;     // sig1+sig2+C2
                const float rv2 = __builtin_amdgcn_rcpf(v2);
                const float cs  = v1 * rv2;
                const float ssim = (2.f*mu12 + C1V) *
                                   __builtin_amdgcn_rcpf(musq + C1V) * cs;
                ssim_acc += ssim;
                cs_acc   += cs;
            }
        }

        // ---- fused 2x2 avg pool of this chunk's 32x32 core (1 out/thread) ----
        if (POOL) {
            const int px = tid & 15, py = tid >> 4;
            const int yy = oy0 + t*32 + 2*py;
            const int xx = ox0 + 2*px;
            const float2 a0 = *(const float2*)(p1 + (size_t)yy*H + xx);
            const float2 a1 = *(const float2*)(p1 + (size_t)(yy+1)*H + xx);
            const float2 b0 = *(const float2*)(p2 + (size_t)yy*H + xx);
            const float2 b1 = *(const float2*)(p2 + (size_t)(yy+1)*H + xx);
            const int h = H >> 1;
            const size_t ob = (size_t)img*h*h +
                              (size_t)(((oy0 + t*32) >> 1) + py)*h + (ox0 >> 1) + px;
            pool1[ob] = 0.25f * (a0.x + a0.y + a1.x + a1.y);
            pool2[ob] = 0.25f * (b0.x + b0.y + b1.x + b1.y);
        }

        // ---- carry: slots 32..41 -> slots 0..9 (10 rows x 32 cols, 2 planes)
        if (t + 1 < CH) {
            __syncthreads();              // col-conv reads of slots 0..9 done
            for (int u = tid; u < 320; u += 256) {
                const int r = u >> 5, c = u & 31;
                rpSD[r][c] = rpSD[32 + r][c];
                rpE2[r][c] = rpE2[32 + r][c];
            }
            __syncthreads();              // carry done before next row-conv
        }
    }

    // ---- deterministic block reduction -> one partial per block ----
#pragma unroll
    for (int off = 32; off > 0; off >>= 1) {
        ssim_acc += __shfl_down(ssim_acc, off);
        cs_acc   += __shfl_down(cs_acc, off);
    }
    const int wave = tid >> 6, lane = tid & 63;
    if (lane == 0) { reds[wave] = ssim_acc; redc[wave] = cs_acc; }
    __syncthreads();
    if (tid == 0) {
        const float s   = reds[0] + reds[1] + reds[2] + reds[3];
        const float cc2 = redc[0] + redc[1] + redc[2] + redc[3];
        partial[(size_t)partial_off + (size_t)blockIdx.y * gridDim.x + blockIdx.x] =
            make_float2(s, cc2);
    }
}

// ---------------- single fused reduce over all levels + final product ----------------
__global__ __launch_bounds__(256) void reduce_final_kernel(
    const float2* __restrict__ partial, ROff ro, float* __restrict__ out)
{
    __shared__ float sS[5], sC[5];
    __shared__ float reds[4], redc[4];
    const int tid = threadIdx.x;
    for (int l = 0; l < 5; ++l) {
        float s = 0.f, c = 0.f;
        for (int i = tid; i < ro.cnt[l]; i += 256) {
            const float2 v = partial[ro.off[l] + i];
            s += v.x; c += v.y;
        }
#pragma unroll
        for (int off = 32; off > 0; off >>= 1) {
            s += __shfl_down(s, off);
            c += __shfl_down(c, off);
        }
        const int wave = tid >> 6, lane = tid & 63;
        if (lane == 0) { reds[wave] = s; redc[wave] = c; }
        __syncthreads();
        if (tid == 0) {
            sS[l] = (reds[0] + reds[1] + reds[2] + reds[3]) * ro.inv[l];
            sC[l] = (redc[0] + redc[1] + redc[2] + redc[3]) * ro.inv[l];
        }
        __syncthreads();
    }
    if (tid == 0) {
        const float w[5] = {0.0448f, 0.2856f, 0.3001f, 0.2363f, 0.1333f};
        float prod = 1.f;
#pragma unroll
        for (int i = 0; i < 4; ++i)
            prod *= powf((sC[i] + 1.f) * 0.5f, w[i]);
        prod *= powf((sS[4] + 1.f) * 0.5f, w[4]);
        out[0] = prod;
    }
}

// ---------------- host launch ----------------
extern "C" void kernel_launch(void* const* d_in, const int* in_sizes, int n_in,
                              void* d_out, int out_size, void* d_ws, size_t ws_size,
                              hipStream_t stream)
{
    const float* img1 = (const float*)d_in[0];
    const float* img2 = (const float*)d_in[1];
    float* out = (float*)d_out;
    float* ws  = (float*)d_ws;

    // Gaussian window (sigma = 1.5), normalized
    Params P;
    {
        double g[WS], sum = 0.0;
        for (int i = 0; i < WS; ++i) {
            double x = (double)i - (WS / 2);
            g[i] = exp(-x * x / (2.0 * 1.5 * 1.5));
            sum += g[i];
        }
        for (int i = 0; i < WS; ++i) P.g[i] = (float)(g[i] / sum);
    }

    // workspace layout: pyramid levels 1..4 (both images), then partials
    float* p1[5]; float* p2[5];
    p1[0] = (float*)img1; p2[0] = (float*)img2;
    size_t o = 0;
    for (int l = 1; l < 5; ++l) {
        const int H = 512 >> l;
        p1[l] = ws + o; o += (size_t)NC * H * H;
        p2[l] = ws + o; o += (size_t)NC * H * H;
    }
    float2* partial = (float2*)(ws + o);
    (void)ws_size; (void)in_sizes; (void)n_in; (void)out_size;

    const int CHv[5] = {4, 2, 1, 1, 1};   // chunks per strip, per level
    ROff ro;
    {
        int off = 0;
        for (int l = 0; l < 5; ++l) {
            const int H = 512 >> l, OH = H - PAD;
            const int tilesX = (OH + 31) / 32;
            const int tilesY = (OH + CHv[l]*32 - 1) / (CHv[l]*32);
            ro.off[l] = off;
            ro.cnt[l] = tilesX * tilesY * NC;
            ro.inv[l] = 1.f / ((float)NC * OH * OH);
            off += ro.cnt[l];
        }
    }

    for (int l = 0; l < 5; ++l) {
        const int H = 512 >> l, OH = H - PAD;
        const int tilesX = (OH + 31) / 32;
        const int tilesY = (OH + CHv[l]*32 - 1) / (CHv[l]*32);
        const dim3 grid(tilesX * tilesY, NC);
        switch (l) {
        case 0:
            ssim_strip_kernel<4,1><<<grid, 256, 0, stream>>>(
                p1[0], p2[0], p1[1], p2[1], H, OH, tilesX, P, partial, ro.off[0]);
            break;
        case 1:
            ssim_strip_kernel<2,1><<<grid, 256, 0, stream>>>(
                p1[1], p2[1], p1[2], p2[2], H, OH, tilesX, P, partial, ro.off[1]);
            break;
        case 2:
            ssim_strip_kernel<1,1><<<grid, 256, 0, stream>>>(
                p1[2], p2[2], p1[3], p2[3], H, OH, tilesX, P, partial, ro.off[2]);
            break;
        case 3:
            ssim_strip_kernel<1,1><<<grid, 256, 0, stream>>>(
                p1[3], p2[3], p1[4], p2[4], H, OH, tilesX, P, partial, ro.off[3]);
            break;
        default:
            ssim_strip_kernel<1,0><<<grid, 256, 0, stream>>>(
                p1[4], p2[4], nullptr, nullptr, H, OH, tilesX, P, partial, ro.off[4]);
            break;
        }
    }

    reduce_final_kernel<<<1, 256, 0, stream>>>(partial, ro, out);
}